// Round 15
// baseline (150.155 us; speedup 1.0000x reference)
//
#include <hip/hip_runtime.h>
#include <hip/hip_bf16.h>
#include <math.h>

#define HWX 16384   // 128*128 pixels per (b, channel) plane

typedef __attribute__((ext_vector_type(8))) short short8v;
typedef __attribute__((ext_vector_type(4))) float f32x4;

__device__ inline ushort f2bf(float x) {
    union { __hip_bfloat16 h; ushort u; } cv;
    cv.h = __float2bfloat16(x);
    return cv.u;
}

// ---------------------------------------------------------------------------
// Pack six 5x5-conv weight sets -> Wpk[oc][k] bf16, k = (ky*5+kx)*64 + ic.
// ---------------------------------------------------------------------------
__global__ __launch_bounds__(256) void packw_kernel(
    const float* __restrict__ w1, const float* __restrict__ b1,
    const float* __restrict__ w2, const float* __restrict__ b2,
    const float* __restrict__ w4, const float* __restrict__ b4,
    const float* __restrict__ w5, const float* __restrict__ b5,
    const float* __restrict__ wz, const float* __restrict__ bz,
    const float* __restrict__ wm, const float* __restrict__ bm,
    __hip_bfloat16* __restrict__ Wpk, float* __restrict__ bpack)
{
    const int idx = blockIdx.x * 256 + threadIdx.x;
    if (idx < 96) {
        const int o = idx; float v = 0.f;
        if      (o < 18) v = b1[o];
        else if (o < 36) v = b2[o - 18];
        else if (o < 54) v = b4[o - 36];
        else if (o < 72) v = b5[o - 54];
        else if (o < 81) v = bz[o - 72];
        else if (o < 90) v = bm[o - 81];
        bpack[o] = v;
    }
    if (idx < 96 * 1600) {
        const int o   = idx / 1600;
        const int k   = idx - o * 1600;
        const int kyx = k >> 6;
        const int ic  = k & 63;
        const int off = ic * 25 + kyx;
        float v = 0.f;
        if      (o < 18) v = w1[o * 1600 + off];
        else if (o < 36) v = w2[(o - 18) * 1600 + off];
        else if (o < 54) v = w4[(o - 36) * 1600 + off];
        else if (o < 72) v = w5[(o - 54) * 1600 + off];
        else if (o < 81) v = wz[(o - 72) * 1600 + off];
        else if (o < 90) v = wm[(o - 81) * 1600 + off];
        Wpk[idx] = __float2bfloat16(v);
    }
}

// ---------------------------------------------------------------------------
// offset_source -> channel-last bf16 with baked-in zero pad ring.
// ---------------------------------------------------------------------------
__global__ __launch_bounds__(256) void packosT_kernel(
    const float* __restrict__ src, __hip_bfloat16* __restrict__ osT)
{
    const int yy = blockIdx.x;
    const int b  = blockIdx.y;
    __hip_bfloat16* dst = osT + ((size_t)b * 132 + yy) * 132 * 64;
    for (int idx = threadIdx.x; idx < 132 * 64; idx += 256) {
        const int xx = idx >> 6;
        const int c  = idx & 63;
        float v = 0.f;
        if (yy >= 2 && yy < 130 && xx >= 2 && xx < 130)
            v = src[(((b << 6) + c) << 14) + ((yy - 2) << 7) + (xx - 2)];
        dst[idx] = __float2bfloat16(v);
    }
}

// ---------------------------------------------------------------------------
// MFMA conv, 2-phase LDS-staged GEMM (validated r11).
// ---------------------------------------------------------------------------
__global__ __launch_bounds__(256) void conv_mfma_kernel(
    const __hip_bfloat16* __restrict__ Wpk,
    const float* __restrict__ bpack,
    const __hip_bfloat16* __restrict__ osT,
    float* __restrict__ offs, float* __restrict__ zbuf, float* __restrict__ mbuf)
{
    __shared__ __align__(16) ushort slab[5 * 68 * 64];
    __shared__ __align__(16) ushort wbuf[2][96 * 64];

    const int bx = blockIdx.x;
    const int y  = bx >> 1;
    const int x0 = (bx & 1) << 6;
    const int b  = blockIdx.y;
    const int t    = threadIdx.x;
    const int wv   = t >> 6;
    const int lane = t & 63;
    const int l15  = lane & 15;
    const int kgrp = lane >> 4;
    const int wm   = wv >> 1;
    const int wn   = wv & 1;

    const ushort* ob = (const ushort*)osT + (size_t)b * (132 * 132 * 64);
    const ushort* Wg = (const ushort*)Wpk;

    for (int c = t; c < 2720; c += 256) {
        const int r5  = c / 544;
        const int rem = c - r5 * 544;
        const int col = rem >> 3;
        const int cb  = rem & 7;
        const short8v v = *(const short8v*)(ob + (((y + r5) * 132 + x0 + col) << 6) + (cb << 3));
        const int slot = r5 * 544 + (col << 3) + (cb ^ (col & 7));
        *(short8v*)((char*)slab + slot * 16) = v;
    }

#define STAGE_W(kyx, bi)                                                       \
    _Pragma("unroll")                                                          \
    for (int it = 0; it < 3; ++it) {                                           \
        const int c  = it * 256 + t;                                           \
        const int oc = c >> 3, cb = c & 7;                                     \
        const ushort* src = Wg + oc * 1600 + (kyx) * 64 + ((cb ^ (oc & 7)) << 3); \
        __builtin_amdgcn_global_load_lds(                                      \
            (const __attribute__((address_space(1))) void*)src,                \
            (__attribute__((address_space(3))) void*)((char*)wbuf[bi] + (it * 256 + wv * 64) * 16), \
            16, 0, 0);                                                         \
    }

    STAGE_W(0, 0)
    __syncthreads();

    f32x4 acc[3][2];
    #pragma unroll
    for (int m = 0; m < 3; ++m)
        #pragma unroll
        for (int n = 0; n < 2; ++n) acc[m][n] = (f32x4){0.f, 0.f, 0.f, 0.f};

    for (int kyx = 0; kyx < 25; ++kyx) {
        const int bi = kyx & 1;
        if (kyx < 24) STAGE_W(kyx + 1, bi ^ 1)
        const int ky = kyx / 5, kx = kyx % 5;
        #pragma unroll
        for (int kc = 0; kc < 2; ++kc) {
            const int kcg = (kc << 2) + kgrp;
            short8v af[3], bf[2];
            #pragma unroll
            for (int m = 0; m < 3; ++m) {
                const int oc = wm * 48 + m * 16 + l15;
                af[m] = *(const short8v*)((char*)wbuf[bi] + ((oc << 3) + (kcg ^ (oc & 7))) * 16);
            }
            #pragma unroll
            for (int n = 0; n < 2; ++n) {
                const int col = wn * 32 + n * 16 + l15 + kx;
                bf[n] = *(const short8v*)((char*)slab + ((ky * 68 + col) * 8 + (kcg ^ (col & 7))) * 16);
            }
            #pragma unroll
            for (int m = 0; m < 3; ++m)
                #pragma unroll
                for (int n = 0; n < 2; ++n)
                    acc[m][n] = __builtin_amdgcn_mfma_f32_16x16x32_bf16(af[m], bf[n], acc[m][n], 0, 0, 0);
        }
        __syncthreads();
    }
#undef STAGE_W

    #pragma unroll
    for (int m = 0; m < 3; ++m) {
        const int ocb = wm * 48 + m * 16 + (kgrp << 2);
        #pragma unroll
        for (int n = 0; n < 2; ++n) {
            const int x = x0 + wn * 32 + n * 16 + l15;
            const int p = (y << 7) + x;
            #pragma unroll
            for (int r = 0; r < 4; ++r) {
                const int o = ocb + r;
                const float v = acc[m][n][r] + bpack[o];
                if (o < 72) {
                    const int i = o / 18, ch = o - i * 18;
                    offs[i * (2 * 18 * HWX) + (((b * 18) + ch) << 14) + p] = v;
                } else if (o < 81) {
                    zbuf[((b * 9 + (o - 72)) << 14) + p] = 3.f / (1.f + expf(-v));
                } else if (o < 90) {
                    mbuf[((b * 9 + (o - 81)) << 14) + p] = 1.f / (1.f + expf(-v));
                }
            }
        }
    }
}

// ---------------------------------------------------------------------------
// Transpose img fp32 -> imgT bf16 channel-last (natural 3D grid).
// ---------------------------------------------------------------------------
__global__ __launch_bounds__(256) void transpose_kernel(
    const float* __restrict__ i0, const float* __restrict__ i1,
    const float* __restrict__ i2, const float* __restrict__ i3,
    ushort* __restrict__ imgT)
{
    const int img = blockIdx.z;
    const int b   = blockIdx.y;
    const int p0  = blockIdx.x << 6;
    const float* src = (img == 0) ? i0 : (img == 1) ? i1 : (img == 2) ? i2 : i3;

    __shared__ float tile[64][65];
    const int t = threadIdx.x;
    const int pp = t & 63, c0 = t >> 6;
    #pragma unroll
    for (int k = 0; k < 16; ++k) {
        const int c = (k << 2) + c0;
        tile[c][pp] = src[(((b << 6) + c) << 14) + p0 + pp];
    }
    __syncthreads();
    const int c2 = t & 31, pl = t >> 5;
    #pragma unroll
    for (int k = 0; k < 8; ++k) {
        const int pi = (k << 3) + pl;
        const uint packed = (uint)f2bf(tile[2 * c2][pi])
                          | ((uint)f2bf(tile[2 * c2 + 1][pi]) << 16);
        *(uint*)(imgT + ((size_t)(((img << 1) + b) << 14) + p0 + pi) * 64 + 2 * c2)
            = packed;
    }
}

// ---------------------------------------------------------------------------
// WcPk[oc][cn'] bf16 with n-major K-order: cn' = n*64 + c  <-  wc[o][c][n].
// (n-major makes each (px,n) 8-channel finalize in fused_dma one contiguous
//  16B LDS write.)
// ---------------------------------------------------------------------------
__global__ __launch_bounds__(256) void wcpk_kernel(
    const float* __restrict__ wc, __hip_bfloat16* __restrict__ WcPk)
{
    const int idx = blockIdx.x * 256 + threadIdx.x;
    if (idx < 36864) {
        const int oc  = idx / 576;
        const int cnp = idx - oc * 576;
        const int n   = cnp >> 6;
        const int c   = cnp & 63;
        WcPk[idx] = __float2bfloat16(wc[oc * 576 + c * 9 + n]);
    }
}

// ---------------------------------------------------------------------------
// Fused deform-sample via DMA-GATHER + MFMA contraction.
// r15: r8-r14 proved VGPR-dest gathers are latency-serialized (~1 in flight,
// compiler-pinned) and TLP doesn't fix it. global_load_lds allows PER-LANE
// global src (only the LDS dest is uniform+lane*16) -> the gather becomes
// issue-and-forget DMA with counted vmcnt (T4), wave-private ring buffer,
// NO barriers in the pipeline loop.
//   block = 32 px (grid 1024), 4 waves; lane = (c8 0..7, pxw 0..7).
//   chunk k = n*4+i: 4 taps x 1KB -> ring region k&3 (16KB/wave).
//   pipeline: issue k+3, s_waitcnt vmcnt(12), process k (4 ds_read_b128 +
//   32 fma into 8-ch acc); finalize at i==3: one b128 write to s_sb[px][n].
// ---------------------------------------------------------------------------
__global__ __launch_bounds__(256) void fused_dma_kernel(
    const float* __restrict__ offs,   // [4][2][18][HWX]
    const float* __restrict__ zbuf,   // [2][9][HWX]
    const float* __restrict__ mbuf,   // [2][9][HWX]
    const ushort* __restrict__ imgT,  // [4][2][HWX][64] bf16
    const __hip_bfloat16* __restrict__ WcPk,  // [64][576] n-major
    float* __restrict__ out)          // [2][64][HWX]
{
    __shared__ __align__(16) uint4  s_tap[32 * 36];        // 18432 B
    __shared__ __align__(16) ushort s_sb[32 * 584];        // 37376 B
    __shared__ __align__(16) char   s_raw[4 * 16384];      // 65536 B  (ring)

    const int t   = threadIdx.x;
    const int pid = blockIdx.x;            // 1024 blocks
    const int b   = pid >> 9;
    const int rem = pid & 511;
    const int h   = rem >> 2;
    const int w0p = (rem & 3) << 5;        // 32-px chunk of the row

    // ---- phase A: taps (32 px x 36 units), packed uint4 ----
    for (int u = t; u < 1152; u += 256) {
        const int px_  = u / 36;
        const int unit = u - px_ * 36;
        const int i    = unit / 9;
        const int n    = unit - i * 9;
        const int wcol = w0p + px_;
        const int p    = (h << 7) + wcol;

        const float* ob = offs + i * (2 * 18 * HWX) + ((b * 18) << 14);
        const float ox = ob[(n << 14) + p];
        const float oy = ob[((n + 9) << 14) + p];
        const float z  = zbuf[((b * 9 + n) << 14) + p];
        const float mm = mbuf[((b * 9 + n) << 14) + p];

        const float zc0 = (i == 0) ? 1.f : 0.f;
        const float zc1 = (i == 0) ? (-11.f / 6.f) : (i == 1) ? 3.f
                         : (i == 2) ? -1.5f : (1.f / 3.f);
        const float zc2 = (i == 0) ? 1.f : (i == 1) ? -2.5f
                         : (i == 2) ? 2.f : -0.5f;
        const float zc3 = (i == 0) ? (-1.f / 6.f) : (i == 1) ? 0.5f
                         : (i == 2) ? -0.5f : (1.f / 6.f);
        const float zw   = zc0 + z * (zc1 + z * (zc2 + z * zc3));
        const float coef = zw * mm;

        const float pxf = (float)(h + n / 3) + ox;
        const float pyf = (float)(wcol + n % 3) + oy;
        const float flx = floorf(pxf), fly = floorf(pyf);
        const float qltx = fminf(fmaxf(flx, 0.f), 129.f);
        const float qrbx = fminf(fmaxf(flx + 1.f, 0.f), 129.f);
        const float qlty = fminf(fmaxf(fly, 0.f), 129.f);
        const float qrby = fminf(fmaxf(fly + 1.f, 0.f), 129.f);
        const float pxc = fminf(fmaxf(pxf, 0.f), 129.f);
        const float pyc = fminf(fmaxf(pyf, 0.f), 129.f);
        const float gxl = 1.f + (qltx - pxc);
        const float gxr = 1.f - (qrbx - pxc);
        const float gyl = 1.f + (qlty - pyc);
        const float gyr = 1.f - (qrby - pyc);
        const int ixl = (int)qltx, ixr = (int)qrbx;
        const int iyl = (int)qlty, iyr = (int)qrby;

        uint i0_, i1_, i2_, i3_, u0_, u1_, u2_, u3_;
        auto mk = [&](int qx, int qy, float g, uint& ii, uint& ww) {
            const bool valid = (qx >= 1) && (qx <= 128) && (qy >= 1) && (qy <= 128);
            ii = valid ? (uint)(((qx - 1) << 7) + (qy - 1)) : 0u;
            ww = valid ? (uint)f2bf(g * coef) : 0u;
        };
        mk(ixl, iyl, gxl * gyl, i0_, u0_);
        mk(ixr, iyr, gxr * gyr, i1_, u1_);
        mk(ixr, iyl, gxr * gyl, i2_, u2_);
        mk(ixl, iyr, gxl * gyr, i3_, u3_);
        uint4 tp;
        tp.x = i0_ | (i1_ << 16);
        tp.y = i2_ | (i3_ << 16);
        tp.z = u0_ | (u1_ << 16);
        tp.w = u2_ | (u3_ << 16);
        s_tap[u] = tp;
    }
    __syncthreads();

    // ---- phase B: DMA-gather pipeline (wave-private, no barriers) ----
    const int lane = t & 63;
    const int wv   = t >> 6;
    const int c8   = lane & 7;
    const int pxw  = lane >> 3;            // 0..7
    const int px   = wv * 8 + pxw;         // 0..31
    const int tapb = px * 36;
    char* rawbase = s_raw + wv * 16384;

    float s8[8];
    #pragma unroll
    for (int m = 0; m < 8; ++m) s8[m] = 0.f;

#define ISSUE(k) {                                                             \
        const int n_ = (k) >> 2, i_ = (k) & 3;                                 \
        const uint4 tp = s_tap[tapb + i_ * 9 + n_];                            \
        const char* ibl = (const char*)imgT + (((size_t)((i_ << 1) + b)) << 21) + c8 * 16; \
        char* dst = rawbase + ((k) & 3) * 4096;                                \
        __builtin_amdgcn_global_load_lds(                                      \
            (const __attribute__((address_space(1))) void*)(ibl + ((tp.x & 0xffffu) << 7)), \
            (__attribute__((address_space(3))) void*)(dst), 16, 0, 0);         \
        __builtin_amdgcn_global_load_lds(                                      \
            (const __attribute__((address_space(1))) void*)(ibl + ((tp.x >> 16) << 7)),     \
            (__attribute__((address_space(3))) void*)(dst + 1024), 16, 0, 0);  \
        __builtin_amdgcn_global_load_lds(                                      \
            (const __attribute__((address_space(1))) void*)(ibl + ((tp.y & 0xffffu) << 7)), \
            (__attribute__((address_space(3))) void*)(dst + 2048), 16, 0, 0);  \
        __builtin_amdgcn_global_load_lds(                                      \
            (const __attribute__((address_space(1))) void*)(ibl + ((tp.y >> 16) << 7)),     \
            (__attribute__((address_space(3))) void*)(dst + 3072), 16, 0, 0);  \
    }

#define PROCESS(k) {                                                           \
        const int n_ = (k) >> 2, i_ = (k) & 3;                                 \
        const uint4 tp = s_tap[tapb + i_ * 9 + n_];                            \
        const char* reg = rawbase + ((k) & 3) * 4096 + lane * 16;              \
        const float wj[4] = { __uint_as_float(tp.z << 16),                     \
                              __uint_as_float(tp.z & 0xffff0000u),             \
                              __uint_as_float(tp.w << 16),                     \
                              __uint_as_float(tp.w & 0xffff0000u) };           \
        _Pragma("unroll")                                                      \
        for (int j = 0; j < 4; ++j) {                                          \
            const uint4 v = *(const uint4*)(reg + j * 1024);                   \
            s8[0] = fmaf(wj[j], __uint_as_float(v.x << 16),         s8[0]);    \
            s8[1] = fmaf(wj[j], __uint_as_float(v.x & 0xffff0000u), s8[1]);    \
            s8[2] = fmaf(wj[j], __uint_as_float(v.y << 16),         s8[2]);    \
            s8[3] = fmaf(wj[j], __uint_as_float(v.y & 0xffff0000u), s8[3]);    \
            s8[4] = fmaf(wj[j], __uint_as_float(v.z << 16),         s8[4]);    \
            s8[5] = fmaf(wj[j], __uint_as_float(v.z & 0xffff0000u), s8[5]);    \
            s8[6] = fmaf(wj[j], __uint_as_float(v.w << 16),         s8[6]);    \
            s8[7] = fmaf(wj[j], __uint_as_float(v.w & 0xffff0000u), s8[7]);    \
        }                                                                      \
        if (i_ == 3) {                                                         \
            uint4 pk;                                                          \
            pk.x = (uint)f2bf(s8[0]) | ((uint)f2bf(s8[1]) << 16);              \
            pk.y = (uint)f2bf(s8[2]) | ((uint)f2bf(s8[3]) << 16);              \
            pk.z = (uint)f2bf(s8[4]) | ((uint)f2bf(s8[5]) << 16);              \
            pk.w = (uint)f2bf(s8[6]) | ((uint)f2bf(s8[7]) << 16);              \
            *(uint4*)((char*)s_sb + px * 1168 + n_ * 128 + c8 * 16) = pk;      \
            _Pragma("unroll")                                                  \
            for (int m = 0; m < 8; ++m) s8[m] = 0.f;                           \
        }                                                                      \
    }

    ISSUE(0) ISSUE(1) ISSUE(2)
    for (int k = 0; k < 33; ++k) {
        ISSUE(k + 3)
        asm volatile("s_waitcnt vmcnt(12)" ::: "memory");
        PROCESS(k)
    }
    asm volatile("s_waitcnt vmcnt(8)" ::: "memory");
    PROCESS(33)
    asm volatile("s_waitcnt vmcnt(4)" ::: "memory");
    PROCESS(34)
    asm volatile("s_waitcnt vmcnt(0)" ::: "memory");
    PROCESS(35)
#undef ISSUE
#undef PROCESS
    __syncthreads();

    // ---- phase C: MFMA contraction; wave wv -> oc block wv*16, 2 px-halves
    const int l15  = lane & 15;
    const int kgrp = lane >> 4;
    const ushort* Wb = (const ushort*)WcPk + (wv * 16 + l15) * 576 + kgrp * 8;
    const char* sb0 = (char*)s_sb + l15 * 1168 + kgrp * 16;
    const char* sb1 = (char*)s_sb + (16 + l15) * 1168 + kgrp * 16;

    f32x4 acc0 = {0.f, 0.f, 0.f, 0.f};
    f32x4 acc1 = {0.f, 0.f, 0.f, 0.f};
    #pragma unroll
    for (int ks = 0; ks < 18; ++ks) {
        const short8v a  = *(const short8v*)(Wb + ks * 32);
        const short8v b0 = *(const short8v*)(sb0 + ks * 64);
        const short8v b1 = *(const short8v*)(sb1 + ks * 64);
        acc0 = __builtin_amdgcn_mfma_f32_16x16x32_bf16(a, b0, acc0, 0, 0, 0);
        acc1 = __builtin_amdgcn_mfma_f32_16x16x32_bf16(a, b1, acc1, 0, 0, 0);
    }

    const int pbase = (h << 7) + w0p;
    #pragma unroll
    for (int r = 0; r < 4; ++r) {
        const int oc = wv * 16 + (kgrp << 2) + r;
        float* orow = out + (((b << 6) + oc) << 14) + pbase;
        orow[l15]      = acc0[r];
        orow[16 + l15] = acc1[r];
    }
}

// ---------------------------------------------------------------------------
extern "C" void kernel_launch(void* const* d_in, const int* in_sizes, int n_in,
                              void* d_out, int out_size, void* d_ws, size_t ws_size,
                              hipStream_t stream) {
    (void)in_sizes; (void)n_in; (void)out_size; (void)ws_size;
    const float* img1  = (const float*)d_in[0];
    const float* img2  = (const float*)d_in[1];
    const float* img4  = (const float*)d_in[2];
    const float* img5  = (const float*)d_in[3];
    const float* osrc  = (const float*)d_in[4];
    const float* w_pc1 = (const float*)d_in[5];
    const float* b_pc1 = (const float*)d_in[6];
    const float* w_pc2 = (const float*)d_in[7];
    const float* b_pc2 = (const float*)d_in[8];
    const float* w_pc4 = (const float*)d_in[9];
    const float* b_pc4 = (const float*)d_in[10];
    const float* w_pc5 = (const float*)d_in[11];
    const float* b_pc5 = (const float*)d_in[12];
    const float* w_z   = (const float*)d_in[13];
    const float* b_z   = (const float*)d_in[14];
    const float* w_m   = (const float*)d_in[15];
    const float* b_m   = (const float*)d_in[16];
    const float* w_cv  = (const float*)d_in[17];
    float* out = (float*)d_out;

    float* wsf  = (float*)d_ws;
    float* offs = wsf;                    // 4 * 589824 floats
    float* zbuf = wsf + 4 * 589824;       // 294912
    float* mbuf = zbuf + 294912;          // 294912
    float* WcTr = mbuf + 294912;          // 36864-float region
    float* imgTr = WcTr + 36864;          // 8388608-float region

    __hip_bfloat16* WcPk  = (__hip_bfloat16*)WcTr;
    ushort*         imgTb = (ushort*)imgTr;

    // Wpk/bpack/osT ALIAS the imgT region (conv pipeline finishes before
    // transpose_kernel overwrites imgT — same-stream serialization).
    __hip_bfloat16* Wpk   = (__hip_bfloat16*)imgTr;            // 153600 bf16
    float*          bpack = imgTr + 76800;                     // 96 f32
    __hip_bfloat16* osT   = (__hip_bfloat16*)(imgTr + 76912);  // 2230272 bf16

    packw_kernel<<<dim3((96 * 1600 + 255) / 256), 256, 0, stream>>>(
        w_pc1, b_pc1, w_pc2, b_pc2, w_pc4, b_pc4, w_pc5, b_pc5,
        w_z, b_z, w_m, b_m, Wpk, bpack);
    packosT_kernel<<<dim3(132, 2), 256, 0, stream>>>(osrc, osT);
    conv_mfma_kernel<<<dim3(256, 2), 256, 0, stream>>>(
        Wpk, bpack, osT, offs, zbuf, mbuf);
    transpose_kernel<<<dim3(256, 2, 4), 256, 0, stream>>>(img1, img2, img4, img5, imgTb);
    wcpk_kernel<<<dim3(144), 256, 0, stream>>>(w_cv, WcPk);
    fused_dma_kernel<<<dim3(1024), 256, 0, stream>>>(offs, zbuf, mbuf, imgTb, WcPk, out);
}

// Round 16
// 104.540 us; speedup vs baseline: 1.4363x; 1.4363x over previous
//
#include <hip/hip_runtime.h>
#include <hip/hip_bf16.h>
#include <math.h>

#define HWX 16384   // 128*128 pixels per (b, channel) plane

typedef __attribute__((ext_vector_type(8))) short short8v;
typedef __attribute__((ext_vector_type(4))) float f32x4;

__device__ inline ushort f2bf(float x) {
    union { __hip_bfloat16 h; ushort u; } cv;
    cv.h = __float2bfloat16(x);
    return cv.u;
}

// ---------------------------------------------------------------------------
// Pack six 5x5-conv weight sets -> Wpk[oc][k] bf16, k = (ky*5+kx)*64 + ic.
// ---------------------------------------------------------------------------
__global__ __launch_bounds__(256) void packw_kernel(
    const float* __restrict__ w1, const float* __restrict__ b1,
    const float* __restrict__ w2, const float* __restrict__ b2,
    const float* __restrict__ w4, const float* __restrict__ b4,
    const float* __restrict__ w5, const float* __restrict__ b5,
    const float* __restrict__ wz, const float* __restrict__ bz,
    const float* __restrict__ wm, const float* __restrict__ bm,
    __hip_bfloat16* __restrict__ Wpk, float* __restrict__ bpack)
{
    const int idx = blockIdx.x * 256 + threadIdx.x;
    if (idx < 96) {
        const int o = idx; float v = 0.f;
        if      (o < 18) v = b1[o];
        else if (o < 36) v = b2[o - 18];
        else if (o < 54) v = b4[o - 36];
        else if (o < 72) v = b5[o - 54];
        else if (o < 81) v = bz[o - 72];
        else if (o < 90) v = bm[o - 81];
        bpack[o] = v;
    }
    if (idx < 96 * 1600) {
        const int o   = idx / 1600;
        const int k   = idx - o * 1600;
        const int kyx = k >> 6;
        const int ic  = k & 63;
        const int off = ic * 25 + kyx;
        float v = 0.f;
        if      (o < 18) v = w1[o * 1600 + off];
        else if (o < 36) v = w2[(o - 18) * 1600 + off];
        else if (o < 54) v = w4[(o - 36) * 1600 + off];
        else if (o < 72) v = w5[(o - 54) * 1600 + off];
        else if (o < 81) v = wz[(o - 72) * 1600 + off];
        else if (o < 90) v = wm[(o - 81) * 1600 + off];
        Wpk[idx] = __float2bfloat16(v);
    }
}

// ---------------------------------------------------------------------------
// offset_source -> channel-last bf16 with baked-in zero pad ring.
// ---------------------------------------------------------------------------
__global__ __launch_bounds__(256) void packosT_kernel(
    const float* __restrict__ src, __hip_bfloat16* __restrict__ osT)
{
    const int yy = blockIdx.x;
    const int b  = blockIdx.y;
    __hip_bfloat16* dst = osT + ((size_t)b * 132 + yy) * 132 * 64;
    for (int idx = threadIdx.x; idx < 132 * 64; idx += 256) {
        const int xx = idx >> 6;
        const int c  = idx & 63;
        float v = 0.f;
        if (yy >= 2 && yy < 130 && xx >= 2 && xx < 130)
            v = src[(((b << 6) + c) << 14) + ((yy - 2) << 7) + (xx - 2)];
        dst[idx] = __float2bfloat16(v);
    }
}

// ---------------------------------------------------------------------------
// MFMA conv, 2-phase LDS-staged GEMM (validated r11).
// ---------------------------------------------------------------------------
__global__ __launch_bounds__(256) void conv_mfma_kernel(
    const __hip_bfloat16* __restrict__ Wpk,
    const float* __restrict__ bpack,
    const __hip_bfloat16* __restrict__ osT,
    float* __restrict__ offs, float* __restrict__ zbuf, float* __restrict__ mbuf)
{
    __shared__ __align__(16) ushort slab[5 * 68 * 64];
    __shared__ __align__(16) ushort wbuf[2][96 * 64];

    const int bx = blockIdx.x;
    const int y  = bx >> 1;
    const int x0 = (bx & 1) << 6;
    const int b  = blockIdx.y;
    const int t    = threadIdx.x;
    const int wv   = t >> 6;
    const int lane = t & 63;
    const int l15  = lane & 15;
    const int kgrp = lane >> 4;
    const int wm   = wv >> 1;
    const int wn   = wv & 1;

    const ushort* ob = (const ushort*)osT + (size_t)b * (132 * 132 * 64);
    const ushort* Wg = (const ushort*)Wpk;

    for (int c = t; c < 2720; c += 256) {
        const int r5  = c / 544;
        const int rem = c - r5 * 544;
        const int col = rem >> 3;
        const int cb  = rem & 7;
        const short8v v = *(const short8v*)(ob + (((y + r5) * 132 + x0 + col) << 6) + (cb << 3));
        const int slot = r5 * 544 + (col << 3) + (cb ^ (col & 7));
        *(short8v*)((char*)slab + slot * 16) = v;
    }

#define STAGE_W(kyx, bi)                                                       \
    _Pragma("unroll")                                                          \
    for (int it = 0; it < 3; ++it) {                                           \
        const int c  = it * 256 + t;                                           \
        const int oc = c >> 3, cb = c & 7;                                     \
        const ushort* src = Wg + oc * 1600 + (kyx) * 64 + ((cb ^ (oc & 7)) << 3); \
        __builtin_amdgcn_global_load_lds(                                      \
            (const __attribute__((address_space(1))) void*)src,                \
            (__attribute__((address_space(3))) void*)((char*)wbuf[bi] + (it * 256 + wv * 64) * 16), \
            16, 0, 0);                                                         \
    }

    STAGE_W(0, 0)
    __syncthreads();

    f32x4 acc[3][2];
    #pragma unroll
    for (int m = 0; m < 3; ++m)
        #pragma unroll
        for (int n = 0; n < 2; ++n) acc[m][n] = (f32x4){0.f, 0.f, 0.f, 0.f};

    for (int kyx = 0; kyx < 25; ++kyx) {
        const int bi = kyx & 1;
        if (kyx < 24) STAGE_W(kyx + 1, bi ^ 1)
        const int ky = kyx / 5, kx = kyx % 5;
        #pragma unroll
        for (int kc = 0; kc < 2; ++kc) {
            const int kcg = (kc << 2) + kgrp;
            short8v af[3], bf[2];
            #pragma unroll
            for (int m = 0; m < 3; ++m) {
                const int oc = wm * 48 + m * 16 + l15;
                af[m] = *(const short8v*)((char*)wbuf[bi] + ((oc << 3) + (kcg ^ (oc & 7))) * 16);
            }
            #pragma unroll
            for (int n = 0; n < 2; ++n) {
                const int col = wn * 32 + n * 16 + l15 + kx;
                bf[n] = *(const short8v*)((char*)slab + ((ky * 68 + col) * 8 + (kcg ^ (col & 7))) * 16);
            }
            #pragma unroll
            for (int m = 0; m < 3; ++m)
                #pragma unroll
                for (int n = 0; n < 2; ++n)
                    acc[m][n] = __builtin_amdgcn_mfma_f32_16x16x32_bf16(af[m], bf[n], acc[m][n], 0, 0, 0);
        }
        __syncthreads();
    }
#undef STAGE_W

    #pragma unroll
    for (int m = 0; m < 3; ++m) {
        const int ocb = wm * 48 + m * 16 + (kgrp << 2);
        #pragma unroll
        for (int n = 0; n < 2; ++n) {
            const int x = x0 + wn * 32 + n * 16 + l15;
            const int p = (y << 7) + x;
            #pragma unroll
            for (int r = 0; r < 4; ++r) {
                const int o = ocb + r;
                const float v = acc[m][n][r] + bpack[o];
                if (o < 72) {
                    const int i = o / 18, ch = o - i * 18;
                    offs[i * (2 * 18 * HWX) + (((b * 18) + ch) << 14) + p] = v;
                } else if (o < 81) {
                    zbuf[((b * 9 + (o - 72)) << 14) + p] = 3.f / (1.f + expf(-v));
                } else if (o < 90) {
                    mbuf[((b * 9 + (o - 81)) << 14) + p] = 1.f / (1.f + expf(-v));
                }
            }
        }
    }
}

// ---------------------------------------------------------------------------
// Transpose img fp32 -> imgT bf16 channel-last.
// ---------------------------------------------------------------------------
__global__ __launch_bounds__(256) void transpose_kernel(
    const float* __restrict__ i0, const float* __restrict__ i1,
    const float* __restrict__ i2, const float* __restrict__ i3,
    ushort* __restrict__ imgT)
{
    const int img = blockIdx.z;
    const int b   = blockIdx.y;
    const int p0  = blockIdx.x << 6;
    const float* src = (img == 0) ? i0 : (img == 1) ? i1 : (img == 2) ? i2 : i3;

    __shared__ float tile[64][65];
    const int t = threadIdx.x;
    const int pp = t & 63, c0 = t >> 6;
    #pragma unroll
    for (int k = 0; k < 16; ++k) {
        const int c = (k << 2) + c0;
        tile[c][pp] = src[(((b << 6) + c) << 14) + p0 + pp];
    }
    __syncthreads();
    const int c2 = t & 31, pl = t >> 5;
    #pragma unroll
    for (int k = 0; k < 8; ++k) {
        const int pi = (k << 3) + pl;
        const uint packed = (uint)f2bf(tile[2 * c2][pi])
                          | ((uint)f2bf(tile[2 * c2 + 1][pi]) << 16);
        *(uint*)(imgT + ((size_t)(((img << 1) + b) << 14) + p0 + pi) * 64 + 2 * c2)
            = packed;
    }
}

// ---------------------------------------------------------------------------
// WcPk[oc][cn'] bf16 with n-major K-order: cn' = n*64 + c  <-  wc[o][c][n].
// ---------------------------------------------------------------------------
__global__ __launch_bounds__(256) void wcpk_kernel(
    const float* __restrict__ wc, __hip_bfloat16* __restrict__ WcPk)
{
    const int idx = blockIdx.x * 256 + threadIdx.x;
    if (idx < 36864) {
        const int oc  = idx / 576;
        const int cnp = idx - oc * 576;
        const int n   = cnp >> 6;
        const int c   = cnp & 63;
        WcPk[idx] = __float2bfloat16(wc[oc * 576 + c * 9 + n]);
    }
}

// ---------------------------------------------------------------------------
// Fused deform-sample + MFMA contraction — WIDE-LOAD variant.
// r6-r15 model: per-wave gather time = (#load instrs) x latency; TLP and
// in-flight depth are both un-raisable. So halve the load count: lane =
// (pxs 0..3, half 0..1, c8 0..7); 16B uint4 loads (8 ch); half h covers
// bilinear taps {2h, 2h+1}; partial sums combined with 8 shfl_xor(8) per
// finalize. 72 loads/thread (was 144), same bytes. s_sb/WcPk n-major so
// each finalize is one contiguous 16B LDS write. LDS 27904 -> 5 blocks/CU.
// ---------------------------------------------------------------------------
__global__ __launch_bounds__(256, 5) void fused_kernel(
    const float* __restrict__ offs,   // [4][2][18][HWX]
    const float* __restrict__ zbuf,   // [2][9][HWX]
    const float* __restrict__ mbuf,   // [2][9][HWX]
    const ushort* __restrict__ imgT,  // [4][2][HWX][64] bf16
    const __hip_bfloat16* __restrict__ WcPk,  // [64][576] n-major
    float* __restrict__ out)          // [2][64][HWX]
{
    __shared__ __hip_bfloat16 s_sb[16 * 584];   // 18688 B
    __shared__ uint4 s_tap[16 * 36];            // 9216 B  => 27904 B

    const int t   = threadIdx.x;
    const int pid = blockIdx.x;
    const int b   = pid >> 10;
    const int rem = pid & 1023;
    const int h   = rem >> 3;
    const int w0p = (rem & 7) << 4;

    // ---- phase A: taps -> packed uint4 ----
    for (int u = t; u < 576; u += 256) {
        const int px_  = u / 36;
        const int unit = u - px_ * 36;
        const int i    = unit / 9;
        const int n    = unit - i * 9;
        const int wcol = w0p + px_;
        const int p    = (h << 7) + wcol;

        const float* ob = offs + i * (2 * 18 * HWX) + ((b * 18) << 14);
        const float ox = ob[(n << 14) + p];
        const float oy = ob[((n + 9) << 14) + p];
        const float z  = zbuf[((b * 9 + n) << 14) + p];
        const float mm = mbuf[((b * 9 + n) << 14) + p];

        const float zc0 = (i == 0) ? 1.f : 0.f;
        const float zc1 = (i == 0) ? (-11.f / 6.f) : (i == 1) ? 3.f
                         : (i == 2) ? -1.5f : (1.f / 3.f);
        const float zc2 = (i == 0) ? 1.f : (i == 1) ? -2.5f
                         : (i == 2) ? 2.f : -0.5f;
        const float zc3 = (i == 0) ? (-1.f / 6.f) : (i == 1) ? 0.5f
                         : (i == 2) ? -0.5f : (1.f / 6.f);
        const float zw   = zc0 + z * (zc1 + z * (zc2 + z * zc3));
        const float coef = zw * mm;

        const float pxf = (float)(h + n / 3) + ox;
        const float pyf = (float)(wcol + n % 3) + oy;
        const float flx = floorf(pxf), fly = floorf(pyf);
        const float qltx = fminf(fmaxf(flx, 0.f), 129.f);
        const float qrbx = fminf(fmaxf(flx + 1.f, 0.f), 129.f);
        const float qlty = fminf(fmaxf(fly, 0.f), 129.f);
        const float qrby = fminf(fmaxf(fly + 1.f, 0.f), 129.f);
        const float pxc = fminf(fmaxf(pxf, 0.f), 129.f);
        const float pyc = fminf(fmaxf(pyf, 0.f), 129.f);
        const float gxl = 1.f + (qltx - pxc);
        const float gxr = 1.f - (qrbx - pxc);
        const float gyl = 1.f + (qlty - pyc);
        const float gyr = 1.f - (qrby - pyc);
        const int ixl = (int)qltx, ixr = (int)qrbx;
        const int iyl = (int)qlty, iyr = (int)qrby;

        uint i0_, i1_, i2_, i3_, u0_, u1_, u2_, u3_;
        auto mk = [&](int qx, int qy, float g, uint& ii, uint& ww) {
            const bool valid = (qx >= 1) && (qx <= 128) && (qy >= 1) && (qy <= 128);
            ii = valid ? (uint)(((qx - 1) << 7) + (qy - 1)) : 0u;
            ww = valid ? (uint)f2bf(g * coef) : 0u;
        };
        mk(ixl, iyl, gxl * gyl, i0_, u0_);
        mk(ixr, iyr, gxr * gyr, i1_, u1_);
        mk(ixr, iyl, gxr * gyl, i2_, u2_);
        mk(ixl, iyr, gxl * gyr, i3_, u3_);
        uint4 tp;
        tp.x = i0_ | (i1_ << 16);
        tp.y = i2_ | (i3_ << 16);
        tp.z = u0_ | (u1_ << 16);
        tp.w = u2_ | (u3_ << 16);
        s_tap[u] = tp;
    }
    __syncthreads();

    // ---- phase B: wide gather, 2 taps per lane-half ----
    const int lane = t & 63;
    const int wv   = t >> 6;
    const int c8   = lane & 7;
    const int half = (lane >> 3) & 1;
    const int pxs  = lane >> 4;
    const int px   = (wv << 2) + pxs;
    const int tb   = px * 36;
    const int cByte = c8 << 4;   // 8 channels * 2B

    #pragma unroll 1
    for (int n = 0; n < 9; ++n) {
        float s8[8];
        #pragma unroll
        for (int m = 0; m < 8; ++m) s8[m] = 0.f;

        #pragma unroll
        for (int i = 0; i < 4; ++i) {
            const uint4 tp = s_tap[tb + i * 9 + n];
            const uint  pair = half ? tp.y : tp.x;   // two tap pixel idxs
            const uint  wpr  = half ? tp.w : tp.z;   // two bf16 weights
            const float wA = __uint_as_float(wpr << 16);
            const float wB = __uint_as_float(wpr & 0xffff0000u);
            const char* ibl = (const char*)imgT + (((size_t)((i << 1) + b)) << 21) + cByte;
            {
                const uint4 v = *(const uint4*)(ibl + ((pair & 0xffffu) << 7));
                s8[0] = fmaf(wA, __uint_as_float(v.x << 16),         s8[0]);
                s8[1] = fmaf(wA, __uint_as_float(v.x & 0xffff0000u), s8[1]);
                s8[2] = fmaf(wA, __uint_as_float(v.y << 16),         s8[2]);
                s8[3] = fmaf(wA, __uint_as_float(v.y & 0xffff0000u), s8[3]);
                s8[4] = fmaf(wA, __uint_as_float(v.z << 16),         s8[4]);
                s8[5] = fmaf(wA, __uint_as_float(v.z & 0xffff0000u), s8[5]);
                s8[6] = fmaf(wA, __uint_as_float(v.w << 16),         s8[6]);
                s8[7] = fmaf(wA, __uint_as_float(v.w & 0xffff0000u), s8[7]);
            }
            {
                const uint4 v = *(const uint4*)(ibl + ((pair >> 16) << 7));
                s8[0] = fmaf(wB, __uint_as_float(v.x << 16),         s8[0]);
                s8[1] = fmaf(wB, __uint_as_float(v.x & 0xffff0000u), s8[1]);
                s8[2] = fmaf(wB, __uint_as_float(v.y << 16),         s8[2]);
                s8[3] = fmaf(wB, __uint_as_float(v.y & 0xffff0000u), s8[3]);
                s8[4] = fmaf(wB, __uint_as_float(v.z << 16),         s8[4]);
                s8[5] = fmaf(wB, __uint_as_float(v.z & 0xffff0000u), s8[5]);
                s8[6] = fmaf(wB, __uint_as_float(v.w << 16),         s8[6]);
                s8[7] = fmaf(wB, __uint_as_float(v.w & 0xffff0000u), s8[7]);
            }
        }

        // combine the two tap-halves (lanes l and l^8 hold partials of the
        // same 8 channels); all lanes end with the full sum
        #pragma unroll
        for (int m = 0; m < 8; ++m) s8[m] += __shfl_xor(s8[m], 8);

        if (half == 0) {
            uint4 pk;
            pk.x = (uint)f2bf(s8[0]) | ((uint)f2bf(s8[1]) << 16);
            pk.y = (uint)f2bf(s8[2]) | ((uint)f2bf(s8[3]) << 16);
            pk.z = (uint)f2bf(s8[4]) | ((uint)f2bf(s8[5]) << 16);
            pk.w = (uint)f2bf(s8[6]) | ((uint)f2bf(s8[7]) << 16);
            *(uint4*)((char*)s_sb + px * 1168 + n * 128 + cByte) = pk;
        }
    }
    __syncthreads();

    // ---- phase C: MFMA contraction (K n-major), wave wv -> oc block wv*16
    const int l15  = lane & 15;
    const int kgrp = lane >> 4;
    const ushort* Wb = (const ushort*)WcPk + (wv * 16 + l15) * 576 + kgrp * 8;
    const ushort* sb = (const ushort*)s_sb + l15 * 584 + kgrp * 8;

    f32x4 acc = {0.f, 0.f, 0.f, 0.f};
    #pragma unroll
    for (int ks = 0; ks < 18; ++ks) {
        const short8v a  = *(const short8v*)(Wb + ks * 32);
        const short8v bb = *(const short8v*)(sb + ks * 32);
        acc = __builtin_amdgcn_mfma_f32_16x16x32_bf16(a, bb, acc, 0, 0, 0);
    }

    const int p = (h << 7) + w0p + l15;
    #pragma unroll
    for (int r = 0; r < 4; ++r) {
        const int oc = wv * 16 + (kgrp << 2) + r;
        out[(((b << 6) + oc) << 14) + p] = acc[r];
    }
}

// ---------------------------------------------------------------------------
extern "C" void kernel_launch(void* const* d_in, const int* in_sizes, int n_in,
                              void* d_out, int out_size, void* d_ws, size_t ws_size,
                              hipStream_t stream) {
    (void)in_sizes; (void)n_in; (void)out_size; (void)ws_size;
    const float* img1  = (const float*)d_in[0];
    const float* img2  = (const float*)d_in[1];
    const float* img4  = (const float*)d_in[2];
    const float* img5  = (const float*)d_in[3];
    const float* osrc  = (const float*)d_in[4];
    const float* w_pc1 = (const float*)d_in[5];
    const float* b_pc1 = (const float*)d_in[6];
    const float* w_pc2 = (const float*)d_in[7];
    const float* b_pc2 = (const float*)d_in[8];
    const float* w_pc4 = (const float*)d_in[9];
    const float* b_pc4 = (const float*)d_in[10];
    const float* w_pc5 = (const float*)d_in[11];
    const float* b_pc5 = (const float*)d_in[12];
    const float* w_z   = (const float*)d_in[13];
    const float* b_z   = (const float*)d_in[14];
    const float* w_m   = (const float*)d_in[15];
    const float* b_m   = (const float*)d_in[16];
    const float* w_cv  = (const float*)d_in[17];
    float* out = (float*)d_out;

    float* wsf  = (float*)d_ws;
    float* offs = wsf;                    // 4 * 589824 floats
    float* zbuf = wsf + 4 * 589824;       // 294912
    float* mbuf = zbuf + 294912;          // 294912
    float* WcTr = mbuf + 294912;          // 36864-float region
    float* imgTr = WcTr + 36864;          // 8388608-float region

    __hip_bfloat16* WcPk  = (__hip_bfloat16*)WcTr;
    ushort*         imgTb = (ushort*)imgTr;

    // Wpk/bpack/osT ALIAS the imgT region (conv pipeline finishes before
    // transpose_kernel overwrites imgT — same-stream serialization).
    __hip_bfloat16* Wpk   = (__hip_bfloat16*)imgTr;            // 153600 bf16
    float*          bpack = imgTr + 76800;                     // 96 f32
    __hip_bfloat16* osT   = (__hip_bfloat16*)(imgTr + 76912);  // 2230272 bf16

    packw_kernel<<<dim3((96 * 1600 + 255) / 256), 256, 0, stream>>>(
        w_pc1, b_pc1, w_pc2, b_pc2, w_pc4, b_pc4, w_pc5, b_pc5,
        w_z, b_z, w_m, b_m, Wpk, bpack);
    packosT_kernel<<<dim3(132, 2), 256, 0, stream>>>(osrc, osT);
    conv_mfma_kernel<<<dim3(256, 2), 256, 0, stream>>>(
        Wpk, bpack, osT, offs, zbuf, mbuf);
    transpose_kernel<<<dim3(256, 2, 4), 256, 0, stream>>>(img1, img2, img4, img5, imgTb);
    wcpk_kernel<<<dim3(144), 256, 0, stream>>>(w_cv, WcPk);
    fused_kernel<<<dim3(2048), 256, 0, stream>>>(offs, zbuf, mbuf, imgTb, WcPk, out);
}